// Round 5
// baseline (36326.154 us; speedup 1.0000x reference)
//
#include <hip/hip_runtime.h>
#include <stdint.h>

// Problem constants
#define Bv 16
#define Sv 2048
#define Iv 128
#define Hv 512
#define Ov 128

typedef __bf16 v8bf __attribute__((ext_vector_type(8)));
typedef float v4f __attribute__((ext_vector_type(4)));
#define MFMA(a, b, c) __builtin_amdgcn_mfma_f32_16x16x32_bf16((a), (b), (c), 0, 0, 0)

__device__ __forceinline__ float sigf(float x) { return 1.0f / (1.0f + __expf(-x)); }
__device__ __forceinline__ float tanh_fast(float x) { return 2.0f / (1.0f + __expf(-2.0f * x)) - 1.0f; }
__device__ __forceinline__ unsigned f2bf(float f) {
  union { __bf16 h; unsigned short u; } c; c.h = (__bf16)f; return (unsigned)c.u;
}
__device__ __forceinline__ float bf2f(unsigned u) {
  union { __bf16 h; unsigned short u; } c; c.u = (unsigned short)u; return (float)c.h;
}
__device__ __forceinline__ v8bf cvt8(const float* p) {
  v8bf r;
#pragma unroll
  for (int i = 0; i < 8; i++) r[i] = (__bf16)p[i];
  return r;
}

// relaxed agent-scope atomics: sc1, bypass non-coherent per-XCD L2, no cache
// maintenance. Coherence point = Infinity Cache.
__device__ __forceinline__ uint64_t ld64(const uint64_t* p) {
  return __hip_atomic_load((uint64_t*)p, __ATOMIC_RELAXED, __HIP_MEMORY_SCOPE_AGENT);
}
__device__ __forceinline__ unsigned ld32(const unsigned* p) {
  return __hip_atomic_load((unsigned*)p, __ATOMIC_RELAXED, __HIP_MEMORY_SCOPE_AGENT);
}
__device__ __forceinline__ void st32(unsigned* p, unsigned v) {
  __hip_atomic_store(p, v, __ATOMIC_RELAXED, __HIP_MEMORY_SCOPE_AGENT);
}

// [lo.b2, lo.b3, hi.b2, hi.b3] : pack two tagged u32s' bf16 halves into one u32
__device__ __forceinline__ unsigned pk(unsigned lo, unsigned hi) {
#if __has_builtin(__builtin_amdgcn_perm)
  return __builtin_amdgcn_perm(hi, lo, 0x07060302u);
#else
  return (lo >> 16) | (hi & 0xffff0000u);
#endif
}

// Consume a full tagged 16x512 slot: per-lane loads are EXACTLY its MFMA
// A-fragment source words. Re-read until every tag matches.
__device__ __forceinline__ void consume(const unsigned* slot, unsigned tag,
                                        int lm, int lq, int j0, bool want_hv,
                                        v8bf* frag, float* hv) {
  const uint64_t* p = (const uint64_t*)slot;
  const int base = lm * 256 + lq * 4;
  uint64_t w[64];
  unsigned hw[4] = {0, 0, 0, 0};
  for (unsigned rr = 0;;) {
#pragma unroll
    for (int kb = 0; kb < 16; kb++)
#pragma unroll
      for (int i = 0; i < 4; i++)
        w[kb * 4 + i] = ld64(p + base + kb * 16 + i);
    if (want_hv) {
#pragma unroll
      for (int v = 0; v < 4; v++) hw[v] = ld32(slot + (lq * 4 + v) * 512 + j0 + lm);
    }
    unsigned acc = 0;
#pragma unroll
    for (int i = 0; i < 64; i++) {
      unsigned lo = (unsigned)w[i], hi = (unsigned)(w[i] >> 32);
      acc |= ((lo ^ tag) & 0xffffu) | ((hi ^ tag) & 0xffffu);
    }
    if (want_hv) {
#pragma unroll
      for (int v = 0; v < 4; v++) acc |= (hw[v] ^ tag) & 0xffffu;
    }
    if (__all(acc == 0) || ++rr > (1u << 20)) break;  // valve: wrong beats hang
    __builtin_amdgcn_s_sleep(1);
  }
#pragma unroll
  for (int kb = 0; kb < 16; kb++) {
    union { v8bf v; unsigned u[4]; } f;
#pragma unroll
    for (int i = 0; i < 4; i++) {
      unsigned lo = (unsigned)w[kb * 4 + i], hi = (unsigned)(w[kb * 4 + i] >> 32);
      f.u[i] = pk(lo, hi);
    }
    frag[kb] = f.v;
  }
  if (want_hv) {
#pragma unroll
    for (int v = 0; v < 4; v++) hv[v] = bf2f(hw[v] >> 16);
  }
}

// Producer: 4 tagged words (C-layout), fire-and-forget.
__device__ __forceinline__ void produce(unsigned* slot, unsigned tag, int lm, int lq,
                                        int j0, const float* vals) {
#pragma unroll
  for (int v = 0; v < 4; v++)
    st32(slot + (lq * 4 + v) * 512 + j0 + lm, (f2bf(vals[v]) << 16) | tag);
}

// Tagged-LDS handoff: tag in low 8 mantissa bits of f32 (rel err ~2^-16).
__device__ __forceinline__ void lds_post(unsigned* buf, int lm, int lq,
                                         const float* vals, unsigned tag8) {
#pragma unroll
  for (int v = 0; v < 4; v++) {
    union { float f; unsigned u; } c; c.f = vals[v];
    __hip_atomic_store(&buf[(lq * 4 + v) * 16 + lm], (c.u & ~255u) | tag8,
                       __ATOMIC_RELAXED, __HIP_MEMORY_SCOPE_WORKGROUP);
  }
}
__device__ __forceinline__ void lds_poll(unsigned* buf, int lm, int lq,
                                         float* vals, unsigned tag8) {
  for (unsigned rr = 0;;) {
    unsigned a[4];
#pragma unroll
    for (int v = 0; v < 4; v++)
      a[v] = __hip_atomic_load(&buf[(lq * 4 + v) * 16 + lm],
                               __ATOMIC_RELAXED, __HIP_MEMORY_SCOPE_WORKGROUP);
    unsigned acc = ((a[0] ^ tag8) | (a[1] ^ tag8) | (a[2] ^ tag8) | (a[3] ^ tag8)) & 255u;
    if (__all(acc == 0) || ++rr > (1u << 20)) {
#pragma unroll
      for (int v = 0; v < 4; v++) {
        union { unsigned u; float f; } c; c.u = a[v] & ~255u; vals[v] = c.f;
      }
      break;
    }
  }
}

// Throttle: wait until this wg's columns of h1 slot carry `tag` (bounds the
// y0-projection waves to <= B2 + 3 steps so LDS rings can't be overrun).
__device__ __forceinline__ void throttle_h1(const unsigned* h1slot, unsigned tag,
                                            int j0, int lm) {
  const unsigned* tp = h1slot + j0 + lm;  // row b=0, own 16 columns
  for (unsigned rr = 0;;) {
    unsigned v = ld32(tp);
    if (__all((v & 0xffffu) == tag) || ++rr > (1u << 20)) break;
    __builtin_amdgcn_s_sleep(1);
  }
}

// x f32 fragment load (A-layout, b=lm) + convert
__device__ __forceinline__ void ldx(const float* x, int t, int lm, int lq, float4* xf) {
#pragma unroll
  for (int kb = 0; kb < 4; kb++) {
    const float* pp = x + ((size_t)lm * Sv + t) * Iv + kb * 32 + lq * 8;
    xf[kb * 2] = *(const float4*)pp;
    xf[kb * 2 + 1] = *(const float4*)(pp + 4);
  }
}
__device__ __forceinline__ void cvx(const float4* xf, v8bf* ax) {
#pragma unroll
  for (int kb = 0; kb < 4; kb++) {
    v8bf a;
    const float* f0 = (const float*)&xf[kb * 2];
    const float* f1 = (const float*)&xf[kb * 2 + 1];
#pragma unroll
    for (int i = 0; i < 4; i++) { a[i] = (__bf16)f0[i]; a[i + 4] = (__bf16)f1[i]; }
    ax[kb] = a;
  }
}

__global__ __launch_bounds__(256, 1) void gru_fused(
    const float* __restrict__ x, const float* __restrict__ hs,
    const float* __restrict__ Wxz0, const float* __restrict__ Whz0, const float* __restrict__ bhz0,
    const float* __restrict__ Wxr0, const float* __restrict__ Whr0, const float* __restrict__ bhr0,
    const float* __restrict__ Wxz1, const float* __restrict__ Whz1, const float* __restrict__ bhz1,
    const float* __restrict__ Wxr1, const float* __restrict__ Whr1, const float* __restrict__ bhr1,
    const float* __restrict__ Why, const float* __restrict__ by,
    float* __restrict__ out, char* __restrict__ ws, int D) {
  const int tid = threadIdx.x;
  const int wv = tid >> 6;
  const int lane = tid & 63;
  const int lm = lane & 15;
  const int lq = lane >> 4;
  const int m0 = D - 1;
  const size_t BSO = (size_t)Bv * Sv * Ov;

  unsigned* prog = (unsigned*)ws;                 // [64] (zeroed by memset)
  unsigned* h0r = (unsigned*)(ws + 4096);         // D slots * 8192 u32
  unsigned* h1r = h0r + (size_t)D * 8192;         // 4 * 8192
  unsigned* u0r = h1r + 4 * 8192;                 // 2 * 8192
  unsigned* u1r = u0r + 2 * 8192;                 // 2 * 8192

  __shared__ unsigned zb[256];        // z handoff (A/A2 -> B/B2), lockstep-safe
  __shared__ unsigned zp[4 * 256];    // L1: A1 zpart ring (y0@Wzx1)
  __shared__ unsigned xp_[4 * 256];   // L1: B1 xrpart ring (y0@Wrx1)

  const bool L0 = (blockIdx.x < 32);
  const int wg = L0 ? blockIdx.x : (blockIdx.x - 32);
  const int j0 = wg << 4;
  const bool OW = (!L0) && (wg < 8);
  const int jrow = j0 + lm;

  if (L0) {
    if (wv == 0) {
      // ===== L0-B: r -> u -> g -> h' (the recurrence driver) =====
      v8bf wrx[4], wrh[16];
#pragma unroll
      for (int kb = 0; kb < 4; kb++) wrx[kb] = cvt8(Wxr0 + (size_t)jrow * Iv + kb * 32 + lq * 8);
#pragma unroll
      for (int kb = 0; kb < 16; kb++) wrh[kb] = cvt8(Whr0 + (size_t)jrow * Hv + kb * 32 + lq * 8);
      float br = bhr0[jrow];
      {  // initial state, tag 1
        float h0v[4];
#pragma unroll
        for (int v = 0; v < 4; v++) h0v[v] = hs[((size_t)(lq * 4 + v) * 2 + 0) * Hv + jrow];
        produce(h0r, 1u, lm, lq, j0, h0v);
      }
      float4 xf[8];
      ldx(x, 0, lm, lq, xf);
      for (int t = 0; t < Sv; ++t) {
        uint64_t pg = 0;
        if (lane < 32) pg = ld64((const uint64_t*)prog + lane);  // speculative
        v8bf ah[16]; float hv[4];
        consume(h0r + (size_t)(t & m0) * 8192, (unsigned)(t + 1), lm, lq, j0, true, ah, hv);
        v8bf ax[4];
        cvx(xf, ax);
        if (t + 1 < Sv) ldx(x, t + 1, lm, lq, xf);  // prefetch
        v4f axr = {0, 0, 0, 0}, a0 = {0, 0, 0, 0}, a1 = {0, 0, 0, 0};
#pragma unroll
        for (int kb = 0; kb < 4; kb++) axr = MFMA(ax[kb], wrx[kb], axr);
#pragma unroll
        for (int kb = 0; kb < 16; kb += 2) {
          a0 = MFMA(ah[kb], wrh[kb], a0);
          a1 = MFMA(ah[kb + 1], wrh[kb + 1], a1);
        }
        float u4[4];
#pragma unroll
        for (int v = 0; v < 4; v++) {
          float r = sigf(axr[v] + a0[v] + a1[v] + br);
          u4[v] = r * hv[v];
        }
        produce(u0r + (t & 1) * 8192, (unsigned)(t + 1), lm, lq, j0, u4);
        if (t >= D && lane < 32) {  // backpressure on y0 ring overwrite
          unsigned need = (unsigned)(t - D + 1);
          for (unsigned rr = 0;;) {
            unsigned pa = (unsigned)pg, pb = (unsigned)(pg >> 32);
            if ((pa >= need && pb >= need) || ++rr > (1u << 20)) break;
            pg = ld64((const uint64_t*)prog + lane);
          }
        }
        v8bf au[16];
        consume(u0r + (size_t)(t & 1) * 8192, (unsigned)(t + 1), lm, lq, j0, false, au, 0);
        v4f g0 = {0, 0, 0, 0}, g1 = {0, 0, 0, 0};
#pragma unroll
        for (int kb = 0; kb < 16; kb += 2) {
          g0 = MFMA(au[kb], wrh[kb], g0);
          g1 = MFMA(au[kb + 1], wrh[kb + 1], g1);
        }
        float zv[4];
        lds_poll(zb, lm, lq, zv, (unsigned)(t + 1) & 255u);
        float hn[4];
#pragma unroll
        for (int v = 0; v < 4; v++) {
          float g = tanh_fast(axr[v] + g0[v] + g1[v] + br);  // faithful source bug
          hn[v] = zv[v] * hv[v] + (1.f - zv[v]) * g;
        }
        if (t == Sv - 1) {
#pragma unroll
          for (int v = 0; v < 4; v++)
            out[BSO + ((size_t)(lq * 4 + v) * 2 + 0) * Hv + jrow] = hn[v];
        }
        produce(h0r + (size_t)((t + 1) & m0) * 8192, (unsigned)(t + 2), lm, lq, j0, hn);
      }
    } else if (wv == 1) {
      // ===== L0-A: z =====
      v8bf wzx[4], wzh[16];
#pragma unroll
      for (int kb = 0; kb < 4; kb++) wzx[kb] = cvt8(Wxz0 + (size_t)jrow * Iv + kb * 32 + lq * 8);
#pragma unroll
      for (int kb = 0; kb < 16; kb++) wzh[kb] = cvt8(Whz0 + (size_t)jrow * Hv + kb * 32 + lq * 8);
      float bz = bhz0[jrow];
#pragma unroll
      for (int i = 0; i < 4; i++)
        __hip_atomic_store(&zb[lane + 64 * i], 0u, __ATOMIC_RELAXED, __HIP_MEMORY_SCOPE_WORKGROUP);
      float4 xf[8];
      ldx(x, 0, lm, lq, xf);
      for (int t = 0; t < Sv; ++t) {
        v8bf ah[16];
        consume(h0r + (size_t)(t & m0) * 8192, (unsigned)(t + 1), lm, lq, j0, false, ah, 0);
        v8bf ax[4];
        cvx(xf, ax);
        if (t + 1 < Sv) ldx(x, t + 1, lm, lq, xf);
        v4f a0 = {0, 0, 0, 0}, a1 = {0, 0, 0, 0};
#pragma unroll
        for (int kb = 0; kb < 4; kb++) a0 = MFMA(ax[kb], wzx[kb], a0);
#pragma unroll
        for (int kb = 0; kb < 16; kb += 2) {
          a0 = MFMA(ah[kb], wzh[kb], a0);
          a1 = MFMA(ah[kb + 1], wzh[kb + 1], a1);
        }
        float zv[4];
#pragma unroll
        for (int v = 0; v < 4; v++) zv[v] = sigf(a0[v] + a1[v] + bz);
        lds_post(zb, lm, lq, zv, (unsigned)(t + 1) & 255u);
      }
    }
    // waves 2,3 idle
  } else {
    if (wv == 0) {
      // ===== L1-B2: r -> u -> g -> h' =====
      v8bf wrh[16];
#pragma unroll
      for (int kb = 0; kb < 16; kb++) wrh[kb] = cvt8(Whr1 + (size_t)jrow * Hv + kb * 32 + lq * 8);
      float br = bhr1[jrow];
      {
        float h0v[4];
#pragma unroll
        for (int v = 0; v < 4; v++) h0v[v] = hs[((size_t)(lq * 4 + v) * 2 + 1) * Hv + jrow];
        produce(h1r, 1u, lm, lq, j0, h0v);
      }
      for (int t = 0; t < Sv; ++t) {
        v8bf ah[16]; float hv[4];
        consume(h1r + (size_t)(t & 3) * 8192, (unsigned)(t + 1), lm, lq, j0, true, ah, hv);
        v4f a0 = {0, 0, 0, 0}, a1 = {0, 0, 0, 0};
#pragma unroll
        for (int kb = 0; kb < 16; kb += 2) {
          a0 = MFMA(ah[kb], wrh[kb], a0);
          a1 = MFMA(ah[kb + 1], wrh[kb + 1], a1);
        }
        float xrp[4];
        lds_poll(xp_ + (t & 3) * 256, lm, lq, xrp, (unsigned)(t + 1) & 255u);
        float u4[4];
#pragma unroll
        for (int v = 0; v < 4; v++) {
          float r = sigf(xrp[v] + a0[v] + a1[v] + br);
          u4[v] = r * hv[v];
        }
        produce(u1r + (t & 1) * 8192, (unsigned)(t + 1), lm, lq, j0, u4);
        v8bf au[16];
        consume(u1r + (size_t)(t & 1) * 8192, (unsigned)(t + 1), lm, lq, j0, false, au, 0);
        v4f g0 = {0, 0, 0, 0}, g1 = {0, 0, 0, 0};
#pragma unroll
        for (int kb = 0; kb < 16; kb += 2) {
          g0 = MFMA(au[kb], wrh[kb], g0);
          g1 = MFMA(au[kb + 1], wrh[kb + 1], g1);
        }
        float zv[4];
        lds_poll(zb, lm, lq, zv, (unsigned)(t + 1) & 255u);
        float hn[4];
#pragma unroll
        for (int v = 0; v < 4; v++) {
          float g = tanh_fast(xrp[v] + g0[v] + g1[v] + br);
          hn[v] = zv[v] * hv[v] + (1.f - zv[v]) * g;
        }
        if (t == Sv - 1) {
#pragma unroll
          for (int v = 0; v < 4; v++)
            out[BSO + ((size_t)(lq * 4 + v) * 2 + 1) * Hv + jrow] = hn[v];
        }
        produce(h1r + (size_t)((t + 1) & 3) * 8192, (unsigned)(t + 2), lm, lq, j0, hn);
      }
    } else if (wv == 1) {
      // ===== L1-B1: xrpart = y0 @ Wrx1^T =====
      v8bf wx[16];
#pragma unroll
      for (int kb = 0; kb < 16; kb++) wx[kb] = cvt8(Wxr1 + (size_t)jrow * Hv + kb * 32 + lq * 8);
      for (int i = lane; i < 1024; i += 64)
        __hip_atomic_store(&xp_[i], 0u, __ATOMIC_RELAXED, __HIP_MEMORY_SCOPE_WORKGROUP);
      for (int t = 0; t < Sv; ++t) {
        v8bf ay[16];
        consume(h0r + (size_t)((t + 1) & m0) * 8192, (unsigned)(t + 2), lm, lq, j0, false, ay, 0);
        if (lane == 0) st32(prog + wg, (unsigned)(t + 1));
        v4f a0 = {0, 0, 0, 0}, a1 = {0, 0, 0, 0};
#pragma unroll
        for (int kb = 0; kb < 16; kb += 2) {
          a0 = MFMA(ay[kb], wx[kb], a0);
          a1 = MFMA(ay[kb + 1], wx[kb + 1], a1);
        }
        float xv[4];
#pragma unroll
        for (int v = 0; v < 4; v++) xv[v] = a0[v] + a1[v];
        if (t >= 3)  // bound run-ahead vs B2 so the xp_ ring can't be overrun
          throttle_h1(h1r + (size_t)((t - 2) & 3) * 8192, (unsigned)(t - 1), j0, lm);
        lds_post(xp_ + (t & 3) * 256, lm, lq, xv, (unsigned)(t + 1) & 255u);
      }
    } else if (wv == 2) {
      // ===== L1-A2: z = sig(zpart + h1@Wzh1 + bz); + out head =====
      v8bf wzh[16], wo[16];
#pragma unroll
      for (int kb = 0; kb < 16; kb++) {
        wzh[kb] = cvt8(Whz1 + (size_t)jrow * Hv + kb * 32 + lq * 8);
        if (OW) wo[kb] = cvt8(Why + (size_t)jrow * Hv + kb * 32 + lq * 8);
      }
      float bz = bhz1[jrow];
      float bo = OW ? by[jrow] : 0.f;
#pragma unroll
      for (int i = 0; i < 4; i++)
        __hip_atomic_store(&zb[lane + 64 * i], 0u, __ATOMIC_RELAXED, __HIP_MEMORY_SCOPE_WORKGROUP);
      for (int t = 0; t < Sv; ++t) {
        v8bf ah[16];
        consume(h1r + (size_t)(t & 3) * 8192, (unsigned)(t + 1), lm, lq, j0, false, ah, 0);
        v4f a0 = {0, 0, 0, 0}, a1 = {0, 0, 0, 0};
#pragma unroll
        for (int kb = 0; kb < 16; kb += 2) {
          a0 = MFMA(ah[kb], wzh[kb], a0);
          a1 = MFMA(ah[kb + 1], wzh[kb + 1], a1);
        }
        float zpv[4];
        lds_poll(zp + (t & 3) * 256, lm, lq, zpv, (unsigned)(t + 1) & 255u);
        float zv[4];
#pragma unroll
        for (int v = 0; v < 4; v++) zv[v] = sigf(zpv[v] + a0[v] + a1[v] + bz);
        lds_post(zb, lm, lq, zv, (unsigned)(t + 1) & 255u);
        if (OW && t > 0) {  // out_{t-1} from y1_{t-1} = this step's h1 frags
          v4f ao = {0, 0, 0, 0};
#pragma unroll
          for (int kb = 0; kb < 16; kb++) ao = MFMA(ah[kb], wo[kb], ao);
#pragma unroll
          for (int v = 0; v < 4; v++)
            out[((size_t)(lq * 4 + v) * Sv + (t - 1)) * Ov + jrow] = ao[v] + bo;
        }
      }
      if (OW) {  // tail: out_{S-1} from final h1 (tag S+1 at slot S&3)
        v8bf ah[16];
        consume(h1r + (size_t)(Sv & 3) * 8192, (unsigned)(Sv + 1), lm, lq, j0, false, ah, 0);
        v4f ao = {0, 0, 0, 0};
#pragma unroll
        for (int kb = 0; kb < 16; kb++) ao = MFMA(ah[kb], wo[kb], ao);
#pragma unroll
        for (int v = 0; v < 4; v++)
          out[((size_t)(lq * 4 + v) * Sv + (Sv - 1)) * Ov + jrow] = ao[v] + bo;
      }
    } else {
      // ===== L1-A1: zpart = y0 @ Wzx1^T =====
      v8bf wx[16];
#pragma unroll
      for (int kb = 0; kb < 16; kb++) wx[kb] = cvt8(Wxz1 + (size_t)jrow * Hv + kb * 32 + lq * 8);
      for (int i = lane; i < 1024; i += 64)
        __hip_atomic_store(&zp[i], 0u, __ATOMIC_RELAXED, __HIP_MEMORY_SCOPE_WORKGROUP);
      for (int t = 0; t < Sv; ++t) {
        v8bf ay[16];
        consume(h0r + (size_t)((t + 1) & m0) * 8192, (unsigned)(t + 2), lm, lq, j0, false, ay, 0);
        if (lane == 0) st32(prog + 32 + wg, (unsigned)(t + 1));
        v4f a0 = {0, 0, 0, 0}, a1 = {0, 0, 0, 0};
#pragma unroll
        for (int kb = 0; kb < 16; kb += 2) {
          a0 = MFMA(ay[kb], wx[kb], a0);
          a1 = MFMA(ay[kb + 1], wx[kb + 1], a1);
        }
        float xv[4];
#pragma unroll
        for (int v = 0; v < 4; v++) xv[v] = a0[v] + a1[v];
        if (t >= 3)  // bound run-ahead vs B2 so the zp ring can't be overrun
          throttle_h1(h1r + (size_t)((t - 2) & 3) * 8192, (unsigned)(t - 1), j0, lm);
        lds_post(zp + (t & 3) * 256, lm, lq, xv, (unsigned)(t + 1) & 255u);
      }
    }
  }
}

extern "C" void kernel_launch(void* const* d_in, const int* in_sizes, int n_in,
                              void* d_out, int out_size, void* d_ws, size_t ws_size,
                              hipStream_t stream) {
  const float* x = (const float*)d_in[0];
  const float* hs = (const float*)d_in[1];
  const float* Wxz0 = (const float*)d_in[2];
  const float* Whz0 = (const float*)d_in[3];
  const float* bhz0 = (const float*)d_in[4];
  const float* Wxr0 = (const float*)d_in[5];
  const float* Whr0 = (const float*)d_in[6];
  const float* bhr0 = (const float*)d_in[7];
  const float* Wxz1 = (const float*)d_in[8];
  const float* Whz1 = (const float*)d_in[9];
  const float* bhz1 = (const float*)d_in[10];
  const float* Wxr1 = (const float*)d_in[11];
  const float* Whr1 = (const float*)d_in[12];
  const float* bhr1 = (const float*)d_in[13];
  const float* Why = (const float*)d_in[14];
  const float* by = (const float*)d_in[15];
  float* out = (float*)d_out;

  // y0-ring depth: largest pow2 (<=64, >=4) fitting ws. Slot = 32 KB tagged.
  int D = 64;
  while (D > 4 && 4096 + (size_t)(D + 8) * 32768 > ws_size) D >>= 1;

  hipMemsetAsync(d_ws, 0, 4096, stream);  // zero progress words
  hipLaunchKernelGGL(gru_fused, dim3(64), dim3(256), 0, stream,
                     x, hs, Wxz0, Whz0, bhz0, Wxr0, Whr0, bhr0,
                     Wxz1, Whz1, bhz1, Wxr1, Whr1, bhr1, Why, by,
                     out, (char*)d_ws, D);
}

// Round 6
// 28807.489 us; speedup vs baseline: 1.2610x; 1.2610x over previous
//
#include <hip/hip_runtime.h>
#include <stdint.h>

// Problem constants
#define Bv 16
#define Sv 2048
#define Iv 128
#define Hv 512
#define Ov 128
#define VALVE (1u << 18)

typedef __bf16 v8bf __attribute__((ext_vector_type(8)));
typedef float v4f __attribute__((ext_vector_type(4)));
#define MFMA(a, b, c) __builtin_amdgcn_mfma_f32_16x16x32_bf16((a), (b), (c), 0, 0, 0)

__device__ __forceinline__ float sigf(float x) { return 1.0f / (1.0f + __expf(-x)); }
__device__ __forceinline__ float tanh_fast(float x) { return 2.0f / (1.0f + __expf(-2.0f * x)) - 1.0f; }
__device__ __forceinline__ unsigned f2bf(float f) {
  union { __bf16 h; unsigned short u; } c; c.h = (__bf16)f; return (unsigned)c.u;
}
__device__ __forceinline__ float bf2f(unsigned u) {
  union { __bf16 h; unsigned short u; } c; c.u = (unsigned short)u; return (float)c.h;
}
__device__ __forceinline__ v8bf cvt8(const float* p) {
  v8bf r;
#pragma unroll
  for (int i = 0; i < 8; i++) r[i] = (__bf16)p[i];
  return r;
}

// relaxed agent-scope atomics: sc1, bypass non-coherent per-XCD L2, no cache
// maintenance ops. Coherence point = Infinity Cache.
__device__ __forceinline__ uint64_t ld64(const uint64_t* p) {
  return __hip_atomic_load((uint64_t*)p, __ATOMIC_RELAXED, __HIP_MEMORY_SCOPE_AGENT);
}
__device__ __forceinline__ unsigned ld32(const unsigned* p) {
  return __hip_atomic_load((unsigned*)p, __ATOMIC_RELAXED, __HIP_MEMORY_SCOPE_AGENT);
}
__device__ __forceinline__ void st32(unsigned* p, unsigned v) {
  __hip_atomic_store(p, v, __ATOMIC_RELAXED, __HIP_MEMORY_SCOPE_AGENT);
}

// [lo.b2, lo.b3, hi.b2, hi.b3]: pack two tagged words' bf16 halves into one u32
__device__ __forceinline__ unsigned pk(unsigned lo, unsigned hi) {
#if __has_builtin(__builtin_amdgcn_perm)
  return __builtin_amdgcn_perm(hi, lo, 0x07060302u);
#else
  return (lo >> 16) | (hi & 0xffff0000u);
#endif
}

// One-shot payload read (fragment-exact, chunked to cap VGPRs) + tag validation.
__device__ __forceinline__ bool try_read(const unsigned* slot, unsigned tag,
                                         int lm, int lq, int j0, bool want_hv,
                                         v8bf* frag, float* hv) {
  const uint64_t* pp = (const uint64_t*)slot;
  const int base = lm * 256 + lq * 4;
  unsigned acc = 0;
  uint64_t buf[16], nxt[16];
#pragma unroll
  for (int i = 0; i < 16; i++) buf[i] = ld64(pp + base + (i >> 2) * 16 + (i & 3));
#pragma unroll
  for (int c = 0; c < 4; c++) {
    if (c < 3) {
#pragma unroll
      for (int i = 0; i < 16; i++)
        nxt[i] = ld64(pp + base + ((c + 1) * 4 + (i >> 2)) * 16 + (i & 3));
    }
#pragma unroll
    for (int k = 0; k < 4; k++) {
      union { v8bf v; unsigned u[4]; } f;
#pragma unroll
      for (int i = 0; i < 4; i++) {
        uint64_t w = buf[k * 4 + i];
        unsigned lo = (unsigned)w, hi = (unsigned)(w >> 32);
        acc |= ((lo ^ tag) & 0xffffu) | ((hi ^ tag) & 0xffffu);
        f.u[i] = pk(lo, hi);
      }
      frag[c * 4 + k] = f.v;
    }
    if (c < 3) {
#pragma unroll
      for (int i = 0; i < 16; i++) buf[i] = nxt[i];
    }
  }
  if (want_hv) {
    unsigned hw[4];
#pragma unroll
    for (int v = 0; v < 4; v++) {
      hw[v] = ld32(slot + (lq * 4 + v) * 512 + j0 + lm);
      acc |= (hw[v] ^ tag) & 0xffffu;
    }
#pragma unroll
    for (int v = 0; v < 4; v++) hv[v] = bf2f(hw[v] >> 16);
  }
  return __all(acc == 0);
}

// cheap-poll spread: one word per lane, 2 per producer, each a producer lane's
// LAST store (rows 3 and 11). 256 B per retry round instead of 32 KB.
__device__ __forceinline__ const unsigned* spread(const unsigned* slot, int lane) {
  int p = lane >> 1, sub = lane & 1;
  return slot + (sub * 8 + 3) * 512 + p * 16 + sub * 8;
}
__device__ __forceinline__ bool spin1(const unsigned* sp, unsigned tag) {
  unsigned rr = 0;
  for (;;) {
    unsigned v = ld32(sp);
    if (__all(((v ^ tag) & 0xffffu) == 0)) return true;
    if (++rr > VALVE) return false;
    __builtin_amdgcn_s_sleep(2);
  }
}
__device__ __forceinline__ bool spin2(const unsigned* sa, unsigned ta,
                                      const unsigned* sb, unsigned tb) {
  unsigned rr = 0;
  for (;;) {
    unsigned a = ld32(sa), b = ld32(sb);
    if (__all((((a ^ ta) | (b ^ tb)) & 0xffffu) == 0)) return true;
    if (++rr > VALVE) return false;
    __builtin_amdgcn_s_sleep(2);
  }
}

__device__ __forceinline__ bool consume1(const unsigned* slot, unsigned tag, int lane,
                                         int lm, int lq, int j0, bool want_hv,
                                         v8bf* frag, float* hv, bool dead) {
  for (int outer = 0;; outer++) {
    if (try_read(slot, tag, lm, lq, j0, want_hv, frag, hv)) return true;
    if (dead || outer >= 64) return false;
    if (!spin1(spread(slot, lane), tag)) return false;
    __builtin_amdgcn_s_sleep(8);
  }
}
__device__ __forceinline__ bool consume2(const unsigned* sA, unsigned tA, v8bf* fA,
                                         const unsigned* sB, unsigned tB, v8bf* fB,
                                         float* hv, int lane, int lm, int lq, int j0,
                                         bool dead) {
  for (int outer = 0;; outer++) {
    bool a = try_read(sA, tA, lm, lq, j0, false, fA, 0);
    bool b = try_read(sB, tB, lm, lq, j0, true, fB, hv);
    if (a && b) return true;
    if (dead || outer >= 64) return false;
    if (!spin2(spread(sA, lane), tA, spread(sB, lane), tB)) return false;
    __builtin_amdgcn_s_sleep(8);
  }
}

// Producer: 4 tagged words (C-layout rows lq*4+v, col j0+lm), fire-and-forget.
__device__ __forceinline__ void produce(unsigned* slot, unsigned tag, int lm, int lq,
                                        int j0, const float* vals) {
#pragma unroll
  for (int v = 0; v < 4; v++)
    st32(slot + (lq * 4 + v) * 512 + j0 + lm, (f2bf(vals[v]) << 16) | tag);
}

// x f32 fragment load (A-layout, b=lm) + convert
__device__ __forceinline__ void ldx(const float* x, int t, int lm, int lq, float4* xf) {
#pragma unroll
  for (int kb = 0; kb < 4; kb++) {
    const float* pp = x + ((size_t)lm * Sv + t) * Iv + kb * 32 + lq * 8;
    xf[kb * 2] = *(const float4*)pp;
    xf[kb * 2 + 1] = *(const float4*)(pp + 4);
  }
}
__device__ __forceinline__ void cvx(const float4* xf, v8bf* ax) {
#pragma unroll
  for (int kb = 0; kb < 4; kb++) {
    v8bf a;
    const float* f0 = (const float*)&xf[kb * 2];
    const float* f1 = (const float*)&xf[kb * 2 + 1];
#pragma unroll
    for (int i = 0; i < 4; i++) { a[i] = (__bf16)f0[i]; a[i + 4] = (__bf16)f1[i]; }
    ax[kb] = a;
  }
}

__global__ __launch_bounds__(64, 1) void gru_fused(
    const float* __restrict__ x, const float* __restrict__ hs,
    const float* __restrict__ Wxz0, const float* __restrict__ Whz0, const float* __restrict__ bhz0,
    const float* __restrict__ Wxr0, const float* __restrict__ Whr0, const float* __restrict__ bhr0,
    const float* __restrict__ Wxz1, const float* __restrict__ Whz1, const float* __restrict__ bhz1,
    const float* __restrict__ Wxr1, const float* __restrict__ Whr1, const float* __restrict__ bhr1,
    const float* __restrict__ Why, const float* __restrict__ by,
    float* __restrict__ out, char* __restrict__ ws, int D) {
  const int lane = threadIdx.x;  // 64-thread blocks: 1 wave each
  const int lm = lane & 15;
  const int lq = lane >> 4;
  const int m0 = D - 1;
  const size_t BSO = (size_t)Bv * Sv * Ov;

  unsigned* prog = (unsigned*)ws;           // [32] L1 y0-consumption progress
  unsigned* oprog = (unsigned*)(ws + 256);  // [8] out-wave h1-consumption progress
  unsigned* h0r = (unsigned*)(ws + 4096);   // D slots * 8192 u32 (32 KB each)
  unsigned* h1r = h0r + (size_t)D * 8192;   // 8 slots
  unsigned* u0r = h1r + 8 * 8192;           // 2 slots
  unsigned* u1r = u0r + 2 * 8192;           // 2 slots

  bool dead = false;
  const int bid = blockIdx.x;

  if (bid < 32) {
    // ============ L0 slice wave: full z,r,u,g,h for cols [j0, j0+16) ============
    const int j0 = bid << 4, jrow = j0 + lm;
    v8bf wrx[4], wzx[4], wrh[16], wzh[16];
#pragma unroll
    for (int kb = 0; kb < 4; kb++) {
      wrx[kb] = cvt8(Wxr0 + (size_t)jrow * Iv + kb * 32 + lq * 8);
      wzx[kb] = cvt8(Wxz0 + (size_t)jrow * Iv + kb * 32 + lq * 8);
    }
#pragma unroll
    for (int kb = 0; kb < 16; kb++) {
      wrh[kb] = cvt8(Whr0 + (size_t)jrow * Hv + kb * 32 + lq * 8);
      wzh[kb] = cvt8(Whz0 + (size_t)jrow * Hv + kb * 32 + lq * 8);
    }
    float br = bhr0[jrow], bz = bhz0[jrow];
    {
      float h0v[4];
#pragma unroll
      for (int v = 0; v < 4; v++) h0v[v] = hs[((size_t)(lq * 4 + v) * 2 + 0) * Hv + jrow];
      produce(h0r, 1u, lm, lq, j0, h0v);
    }
    float4 xf[8];
    ldx(x, 0, lm, lq, xf);
    for (int t = 0; t < Sv; ++t) {
      v8bf ah[16]; float hvv[4];
      dead |= !consume1(h0r + (size_t)(t & m0) * 8192, (unsigned)(t + 1),
                        lane, lm, lq, j0, true, ah, hvv, dead);
      v8bf ax[4];
      cvx(xf, ax);
      v4f axr = {0, 0, 0, 0}, r0 = {0, 0, 0, 0}, r1 = {0, 0, 0, 0};
#pragma unroll
      for (int kb = 0; kb < 4; kb++) axr = MFMA(ax[kb], wrx[kb], axr);
#pragma unroll
      for (int kb = 0; kb < 16; kb += 2) {
        r0 = MFMA(ah[kb], wrh[kb], r0);
        r1 = MFMA(ah[kb + 1], wrh[kb + 1], r1);
      }
      float u4[4];
#pragma unroll
      for (int v = 0; v < 4; v++) {
        float r = sigf(axr[v] + r0[v] + r1[v] + br);
        u4[v] = r * hvv[v];
      }
      produce(u0r + (t & 1) * 8192, (unsigned)(t + 1), lm, lq, j0, u4);
      // ---- u-wait shadow: z matvec + x prefetch ----
      v4f z0 = {0, 0, 0, 0}, z1 = {0, 0, 0, 0};
#pragma unroll
      for (int kb = 0; kb < 4; kb++) z0 = MFMA(ax[kb], wzx[kb], z0);
#pragma unroll
      for (int kb = 0; kb < 16; kb += 2) {
        z0 = MFMA(ah[kb], wzh[kb], z0);
        z1 = MFMA(ah[kb + 1], wzh[kb + 1], z1);
      }
      if (t + 1 < Sv) ldx(x, t + 1, lm, lq, xf);
      if (t >= D) {  // backpressure: L1 must have consumed y0(t-D)
        unsigned need = (unsigned)(t - D + 1), rr = 0;
        for (;;) {
          unsigned pv = (lane < 32) ? ld32(prog + lane) : 0xffffffffu;
          if (__all(pv >= need)) break;
          if (++rr > VALVE) { dead = true; break; }
          __builtin_amdgcn_s_sleep(2);
        }
      }
      v8bf au[16];
      dead |= !consume1(u0r + (size_t)(t & 1) * 8192, (unsigned)(t + 1),
                        lane, lm, lq, j0, false, au, 0, dead);
      v4f g0 = {0, 0, 0, 0}, g1 = {0, 0, 0, 0};
#pragma unroll
      for (int kb = 0; kb < 16; kb += 2) {
        g0 = MFMA(au[kb], wrh[kb], g0);
        g1 = MFMA(au[kb + 1], wrh[kb + 1], g1);
      }
      float hn[4];
#pragma unroll
      for (int v = 0; v < 4; v++) {
        float zv = sigf(z0[v] + z1[v] + bz);
        float g = tanh_fast(axr[v] + g0[v] + g1[v] + br);  // faithful source bug
        hn[v] = zv * hvv[v] + (1.f - zv) * g;
      }
      if (t == Sv - 1) {
#pragma unroll
        for (int v = 0; v < 4; v++)
          out[BSO + ((size_t)(lq * 4 + v) * 2 + 0) * Hv + jrow] = hn[v];
      }
      produce(h0r + (size_t)((t + 1) & m0) * 8192, (unsigned)(t + 2), lm, lq, j0, hn);
    }
  } else if (bid < 64) {
    // ============ L1 slice wave (z-weights streamed in the u-wait shadow) ============
    const int wg = bid - 32, j0 = wg << 4, jrow = j0 + lm;
    v8bf wrx[16], wrh[16];
#pragma unroll
    for (int kb = 0; kb < 16; kb++) {
      wrx[kb] = cvt8(Wxr1 + (size_t)jrow * Hv + kb * 32 + lq * 8);
      wrh[kb] = cvt8(Whr1 + (size_t)jrow * Hv + kb * 32 + lq * 8);
    }
    float br = bhr1[jrow], bz = bhz1[jrow];
    {
      float h0v[4];
#pragma unroll
      for (int v = 0; v < 4; v++) h0v[v] = hs[((size_t)(lq * 4 + v) * 2 + 1) * Hv + jrow];
      produce(h1r, 1u, lm, lq, j0, h0v);
    }
    for (int t = 0; t < Sv; ++t) {
      v8bf ay[16], ah[16]; float hvv[4];
      dead |= !consume2(h0r + (size_t)((t + 1) & m0) * 8192, (unsigned)(t + 2), ay,
                        h1r + (size_t)(t & 7) * 8192, (unsigned)(t + 1), ah, hvv,
                        lane, lm, lq, j0, dead);
      if (lane == 0) st32(prog + wg, (unsigned)(t + 1));  // y0(t) consumed
      v4f axr0 = {0, 0, 0, 0}, axr1 = {0, 0, 0, 0}, ahr0 = {0, 0, 0, 0}, ahr1 = {0, 0, 0, 0};
#pragma unroll
      for (int kb = 0; kb < 16; kb += 2) {
        axr0 = MFMA(ay[kb], wrx[kb], axr0);
        axr1 = MFMA(ay[kb + 1], wrx[kb + 1], axr1);
        ahr0 = MFMA(ah[kb], wrh[kb], ahr0);
        ahr1 = MFMA(ah[kb + 1], wrh[kb + 1], ahr1);
      }
      float xr[4], u4[4];
#pragma unroll
      for (int v = 0; v < 4; v++) {
        xr[v] = axr0[v] + axr1[v];
        float r = sigf(xr[v] + ahr0[v] + ahr1[v] + br);
        u4[v] = r * hvv[v];
      }
      produce(u1r + (t & 1) * 8192, (unsigned)(t + 1), lm, lq, j0, u4);
      // ---- u-wait shadow: z matvec with streamed (L2-hot) weights ----
      v4f z0 = {0, 0, 0, 0}, z1 = {0, 0, 0, 0};
#pragma unroll
      for (int kb = 0; kb < 16; kb++) {
        v8bf wa = cvt8(Wxz1 + (size_t)jrow * Hv + kb * 32 + lq * 8);
        v8bf wb = cvt8(Whz1 + (size_t)jrow * Hv + kb * 32 + lq * 8);
        z0 = MFMA(ay[kb], wa, z0);
        z1 = MFMA(ah[kb], wb, z1);
      }
      if (t >= 7) {  // backpressure: out-waves must have consumed h1(t-7)
        unsigned need = (unsigned)(t - 6), rr = 0;
        for (;;) {
          unsigned pv = (lane < 8) ? ld32(oprog + lane) : 0xffffffffu;
          if (__all(pv >= need)) break;
          if (++rr > VALVE) { dead = true; break; }
          __builtin_amdgcn_s_sleep(2);
        }
      }
      v8bf au[16];
      dead |= !consume1(u1r + (size_t)(t & 1) * 8192, (unsigned)(t + 1),
                        lane, lm, lq, j0, false, au, 0, dead);
      v4f g0 = {0, 0, 0, 0}, g1 = {0, 0, 0, 0};
#pragma unroll
      for (int kb = 0; kb < 16; kb += 2) {
        g0 = MFMA(au[kb], wrh[kb], g0);
        g1 = MFMA(au[kb + 1], wrh[kb + 1], g1);
      }
      float hn[4];
#pragma unroll
      for (int v = 0; v < 4; v++) {
        float zv = sigf(z0[v] + z1[v] + bz);
        float g = tanh_fast(xr[v] + g0[v] + g1[v] + br);
        hn[v] = zv * hvv[v] + (1.f - zv) * g;
      }
      if (t == Sv - 1) {
#pragma unroll
        for (int v = 0; v < 4; v++)
          out[BSO + ((size_t)(lq * 4 + v) * 2 + 1) * Hv + jrow] = hn[v];
      }
      produce(h1r + (size_t)((t + 1) & 7) * 8192, (unsigned)(t + 2), lm, lq, j0, hn);
    }
  } else {
    // ============ out-head wave: out(t-1) = y1(t-1)@Why^T + by ============
    const int o = bid - 64, j0 = o << 4, orow = j0 + lm;
    v8bf wo[16];
#pragma unroll
    for (int kb = 0; kb < 16; kb++)
      wo[kb] = cvt8(Why + (size_t)orow * Hv + kb * 32 + lq * 8);
    float bo = by[orow];
    for (int t = 0; t <= Sv; ++t) {
      v8bf ah[16];
      dead |= !consume1(h1r + (size_t)(t & 7) * 8192, (unsigned)(t + 1),
                        lane, lm, lq, j0, false, ah, 0, dead);
      if (lane == 0) st32(oprog + o, (unsigned)(t + 1));
      if (t > 0) {
        v4f a0 = {0, 0, 0, 0}, a1 = {0, 0, 0, 0};
#pragma unroll
        for (int kb = 0; kb < 16; kb += 2) {
          a0 = MFMA(ah[kb], wo[kb], a0);
          a1 = MFMA(ah[kb + 1], wo[kb + 1], a1);
        }
#pragma unroll
        for (int v = 0; v < 4; v++)
          out[((size_t)(lq * 4 + v) * Sv + (t - 1)) * Ov + orow] = a0[v] + a1[v] + bo;
      }
    }
  }
}

extern "C" void kernel_launch(void* const* d_in, const int* in_sizes, int n_in,
                              void* d_out, int out_size, void* d_ws, size_t ws_size,
                              hipStream_t stream) {
  const float* x = (const float*)d_in[0];
  const float* hs = (const float*)d_in[1];
  const float* Wxz0 = (const float*)d_in[2];
  const float* Whz0 = (const float*)d_in[3];
  const float* bhz0 = (const float*)d_in[4];
  const float* Wxr0 = (const float*)d_in[5];
  const float* Whr0 = (const float*)d_in[6];
  const float* bhr0 = (const float*)d_in[7];
  const float* Wxz1 = (const float*)d_in[8];
  const float* Whz1 = (const float*)d_in[9];
  const float* bhz1 = (const float*)d_in[10];
  const float* Wxr1 = (const float*)d_in[11];
  const float* Whr1 = (const float*)d_in[12];
  const float* bhr1 = (const float*)d_in[13];
  const float* Why = (const float*)d_in[14];
  const float* by = (const float*)d_in[15];
  float* out = (float*)d_out;

  // y0-ring depth: largest pow2 (<=64, >=4) fitting ws. Slot = 32 KB tagged.
  int D = 64;
  while (D > 4 && 4096 + (size_t)(D + 12) * 32768 > ws_size) D >>= 1;

  hipMemsetAsync(d_ws, 0, 4096, stream);  // zero prog/oprog
  hipLaunchKernelGGL(gru_fused, dim3(72), dim3(64), 0, stream,
                     x, hs, Wxz0, Whz0, bhz0, Wxr0, Whr0, bhr0,
                     Wxz1, Whz1, bhz1, Wxr1, Whr1, bhr1, Why, by,
                     out, (char*)d_ws, D);
}

// Round 7
// 19144.475 us; speedup vs baseline: 1.8975x; 1.5047x over previous
//
#include <hip/hip_runtime.h>
#include <stdint.h>

// Problem constants
#define Bv 16
#define Sv 2048
#define Iv 128
#define Hv 512
#define Ov 128
#define VALVE (1u << 18)

typedef __bf16 v8bf __attribute__((ext_vector_type(8)));
typedef float v4f __attribute__((ext_vector_type(4)));
#define MFMA(a, b, c) __builtin_amdgcn_mfma_f32_16x16x32_bf16((a), (b), (c), 0, 0, 0)

__device__ __forceinline__ float sigf(float x) { return 1.0f / (1.0f + __expf(-x)); }
__device__ __forceinline__ float tanh_fast(float x) { return 2.0f / (1.0f + __expf(-2.0f * x)) - 1.0f; }
__device__ __forceinline__ unsigned f2bf(float f) {
  union { __bf16 h; unsigned short u; } c; c.h = (__bf16)f; return (unsigned)c.u;
}
__device__ __forceinline__ float bf2f(unsigned u) {
  union { __bf16 h; unsigned short u; } c; c.u = (unsigned short)u; return (float)c.h;
}
__device__ __forceinline__ v8bf cvt8(const float* p) {
  v8bf r;
#pragma unroll
  for (int i = 0; i < 8; i++) r[i] = (__bf16)p[i];
  return r;
}

// relaxed agent-scope atomics: sc1, bypass non-coherent per-XCD L2, no cache
// maintenance ops. Coherence point = Infinity Cache.
__device__ __forceinline__ uint64_t ld64(const uint64_t* p) {
  return __hip_atomic_load((uint64_t*)p, __ATOMIC_RELAXED, __HIP_MEMORY_SCOPE_AGENT);
}
__device__ __forceinline__ unsigned ld32(const unsigned* p) {
  return __hip_atomic_load((unsigned*)p, __ATOMIC_RELAXED, __HIP_MEMORY_SCOPE_AGENT);
}
__device__ __forceinline__ void st32(unsigned* p, unsigned v) {
  __hip_atomic_store(p, v, __ATOMIC_RELAXED, __HIP_MEMORY_SCOPE_AGENT);
}

// [lo.b2, lo.b3, hi.b2, hi.b3]: pack two tagged words' bf16 halves into one u32
__device__ __forceinline__ unsigned pk(unsigned lo, unsigned hi) {
#if __has_builtin(__builtin_amdgcn_perm)
  return __builtin_amdgcn_perm(hi, lo, 0x07060302u);
#else
  return (lo >> 16) | (hi & 0xffff0000u);
#endif
}

// ==== Fragment-major tagged slot layout (8192 dwords / 32 KB per slot) ====
// Element (b, j):  kb=j>>5, r=j&31, lqc=r>>3, i=r&7, half=i>>2, d=i&3
//   dword index = kb*512 + half*256 + lqc*64 + b*4 + d   (tag16 | bf16<<16)
// A consuming lane (lane = lq*16+lm) reads, per kb, dwords
//   kb*512 + half*256 + lane*4 + d  -> 64 lanes are CONTIGUOUS (coalesced).

// One-shot coalesced payload read + tag validation (chunked: 32 regs live).
__device__ __forceinline__ bool try_read(const unsigned* slot, unsigned tag, int lane,
                                         v8bf* frag, int base_p, int lq, bool want_hv,
                                         float* hv) {
  const uint64_t* p64 = (const uint64_t*)slot;
  unsigned acc = 0;
#pragma unroll
  for (int c = 0; c < 4; c++) {
    uint64_t w[16];
#pragma unroll
    for (int k = 0; k < 4; k++) {
      const uint64_t* q = p64 + (size_t)(c * 4 + k) * 256 + lane * 2;
      w[k * 4 + 0] = ld64(q);
      w[k * 4 + 1] = ld64(q + 1);
      w[k * 4 + 2] = ld64(q + 128);
      w[k * 4 + 3] = ld64(q + 129);
    }
#pragma unroll
    for (int k = 0; k < 4; k++) {
      union { v8bf v; unsigned u[4]; } f;
#pragma unroll
      for (int d2 = 0; d2 < 4; d2++) {
        uint64_t ww = w[k * 4 + d2];
        unsigned lo = (unsigned)ww, hi = (unsigned)(ww >> 32);
        acc |= ((lo ^ tag) & 0xffffu) | ((hi ^ tag) & 0xffffu);
        f.u[d2] = pk(lo, hi);
      }
      frag[c * 4 + k] = f.v;
    }
  }
  if (want_hv) {
#pragma unroll
    for (int v = 0; v < 4; v++) {
      unsigned hw = ld32(slot + base_p + (lq * 4 + v) * 4);
      acc |= (hw ^ tag) & 0xffffu;
      hv[v] = bf2f(hw >> 16);
    }
  }
  return __all(acc == 0);
}

// Cheap spin: 1 dword/lane (32 producers x duplicated), ~32 lines per round.
__device__ __forceinline__ bool spin(const unsigned* probe, unsigned tag) {
  unsigned rr = 0;
  for (;;) {
    unsigned v = ld32(probe);
    if (__all(((v ^ tag) & 0xffffu) == 0)) return true;
    if (++rr > VALVE) return false;
    __builtin_amdgcn_s_sleep(1);
  }
}

__device__ __forceinline__ bool consume(const unsigned* slot, unsigned tag, int lane,
                                        int probe_off, v8bf* frag, int base_p, int lq,
                                        bool want_hv, float* hv, bool dead) {
  if (!dead && !spin(slot + probe_off, tag)) dead = true;
  for (int a = 0;; a++) {
    if (try_read(slot, tag, lane, frag, base_p, lq, want_hv, hv)) return true;
    if (dead || a >= 32) return false;  // valve: wrong answer beats hang
    __builtin_amdgcn_s_sleep(2);
  }
}

// Producer: 4 tagged dwords, fire-and-forget.
__device__ __forceinline__ void produce(unsigned* slot, unsigned tag, int base_p,
                                        int lq, const float* vals) {
#pragma unroll
  for (int v = 0; v < 4; v++)
    st32(slot + base_p + (lq * 4 + v) * 4, (f2bf(vals[v]) << 16) | tag);
}

// x f32 fragment load (A-layout, b=lm) + convert
__device__ __forceinline__ void ldx(const float* x, int t, int lm, int lq, float4* xf) {
#pragma unroll
  for (int kb = 0; kb < 4; kb++) {
    const float* pp = x + ((size_t)lm * Sv + t) * Iv + kb * 32 + lq * 8;
    xf[kb * 2] = *(const float4*)pp;
    xf[kb * 2 + 1] = *(const float4*)(pp + 4);
  }
}
__device__ __forceinline__ void cvx(const float4* xf, v8bf* ax) {
#pragma unroll
  for (int kb = 0; kb < 4; kb++) {
    v8bf a;
    const float* f0 = (const float*)&xf[kb * 2];
    const float* f1 = (const float*)&xf[kb * 2 + 1];
#pragma unroll
    for (int i = 0; i < 4; i++) { a[i] = (__bf16)f0[i]; a[i + 4] = (__bf16)f1[i]; }
    ax[kb] = a;
  }
}

__global__ __launch_bounds__(64, 1) void gru_fused(
    const float* __restrict__ x, const float* __restrict__ hs,
    const float* __restrict__ Wxz0, const float* __restrict__ Whz0, const float* __restrict__ bhz0,
    const float* __restrict__ Wxr0, const float* __restrict__ Whr0, const float* __restrict__ bhr0,
    const float* __restrict__ Wxz1, const float* __restrict__ Whz1, const float* __restrict__ bhz1,
    const float* __restrict__ Wxr1, const float* __restrict__ Whr1, const float* __restrict__ bhr1,
    const float* __restrict__ Why, const float* __restrict__ by,
    float* __restrict__ out, char* __restrict__ ws, int D) {
  const int lane = threadIdx.x;  // 64-thread blocks: one wave each
  const int lm = lane & 15;
  const int lq = lane >> 4;
  const int m0 = D - 1;
  const size_t BSO = (size_t)Bv * Sv * Ov;

  unsigned* prog = (unsigned*)ws;           // [32] L1 y0-consumption progress
  unsigned* oprog = (unsigned*)(ws + 256);  // [8] out-wave h1-consumption progress
  unsigned* h0r = (unsigned*)(ws + 4096);   // D slots * 8192 u32
  unsigned* h1r = h0r + (size_t)D * 8192;   // 8 slots
  unsigned* u0r = h1r + 8 * 8192;           // 2 slots
  unsigned* u1r = u0r + 2 * 8192;           // 2 slots

  // per-lane probe word: producer p = lane&31's program-order-last store
  const int pp_ = lane & 31;
  const int jp = pp_ * 16 + 15;
  const int probe_off = (jp >> 5) * 512 + 256 + ((jp & 31) >> 3) * 64 + 63;

  bool dead = false;
  const int bid = blockIdx.x;

  if (bid < 32) {
    // ========== L0 slice wave: full z,r,u,g,h for cols [j0, j0+16) ==========
    const int j0 = bid << 4, jrow = j0 + lm;
    const int jj = jrow;
    const int base_p = (jj >> 5) * 512 + ((jj & 7) >> 2) * 256 + ((jj & 31) >> 3) * 64 + (jj & 3);
    v8bf wrx[4], wrh[16];
#pragma unroll
    for (int kb = 0; kb < 4; kb++) wrx[kb] = cvt8(Wxr0 + (size_t)jrow * Iv + kb * 32 + lq * 8);
#pragma unroll
    for (int kb = 0; kb < 16; kb++) wrh[kb] = cvt8(Whr0 + (size_t)jrow * Hv + kb * 32 + lq * 8);
    float br = bhr0[jrow], bz = bhz0[jrow];
    {
      float h0v[4];
#pragma unroll
      for (int v = 0; v < 4; v++) h0v[v] = hs[((size_t)(lq * 4 + v) * 2 + 0) * Hv + jrow];
      produce(h0r, 1u, base_p, lq, h0v);
    }
    float4 xf[8];
    ldx(x, 0, lm, lq, xf);
    for (int t = 0; t < Sv; ++t) {
      v8bf ah[16]; float hvv[4];
      dead |= !consume(h0r + (size_t)(t & m0) * 8192, (unsigned)(t + 1), lane, probe_off,
                       ah, base_p, lq, true, hvv, dead);
      v8bf ax[4];
      cvx(xf, ax);
      v4f axr = {0, 0, 0, 0}, r0 = {0, 0, 0, 0}, r1 = {0, 0, 0, 0};
#pragma unroll
      for (int kb = 0; kb < 4; kb++) axr = MFMA(ax[kb], wrx[kb], axr);
#pragma unroll
      for (int kb = 0; kb < 16; kb += 2) {
        r0 = MFMA(ah[kb], wrh[kb], r0);
        r1 = MFMA(ah[kb + 1], wrh[kb + 1], r1);
      }
      float u4[4];
#pragma unroll
      for (int v = 0; v < 4; v++) {
        float r = sigf(axr[v] + r0[v] + r1[v] + br);
        u4[v] = r * hvv[v];
      }
      produce(u0r + (t & 1) * 8192, (unsigned)(t + 1), base_p, lq, u4);
      // ---- u-wait shadow: z matvec (streamed L2-hot weights) + x prefetch ----
      v4f z0 = {0, 0, 0, 0}, z1 = {0, 0, 0, 0};
#pragma unroll
      for (int kb = 0; kb < 4; kb++)
        z0 = MFMA(ax[kb], cvt8(Wxz0 + (size_t)jrow * Iv + kb * 32 + lq * 8), z0);
#pragma unroll
      for (int kb = 0; kb < 16; kb += 2) {
        z0 = MFMA(ah[kb], cvt8(Whz0 + (size_t)jrow * Hv + kb * 32 + lq * 8), z0);
        z1 = MFMA(ah[kb + 1], cvt8(Whz0 + (size_t)jrow * Hv + (kb + 1) * 32 + lq * 8), z1);
      }
      if (t + 1 < Sv) ldx(x, t + 1, lm, lq, xf);
      if (t >= D) {  // backpressure: L1 must have consumed y0(t-D)
        unsigned need = (unsigned)(t - D + 1), rr = 0;
        for (;;) {
          unsigned pv = (lane < 32) ? ld32(prog + lane) : 0xffffffffu;
          if (__all(pv >= need)) break;
          if (++rr > VALVE) { dead = true; break; }
          __builtin_amdgcn_s_sleep(1);
        }
      }
      v8bf au[16];
      dead |= !consume(u0r + (size_t)(t & 1) * 8192, (unsigned)(t + 1), lane, probe_off,
                       au, 0, lq, false, 0, dead);
      v4f g0 = {0, 0, 0, 0}, g1 = {0, 0, 0, 0};
#pragma unroll
      for (int kb = 0; kb < 16; kb += 2) {
        g0 = MFMA(au[kb], wrh[kb], g0);
        g1 = MFMA(au[kb + 1], wrh[kb + 1], g1);
      }
      float hn[4];
#pragma unroll
      for (int v = 0; v < 4; v++) {
        float zv = sigf(z0[v] + z1[v] + bz);
        float g = tanh_fast(axr[v] + g0[v] + g1[v] + br);  // faithful source bug
        hn[v] = zv * hvv[v] + (1.f - zv) * g;
      }
      if (t == Sv - 1) {
#pragma unroll
        for (int v = 0; v < 4; v++)
          out[BSO + ((size_t)(lq * 4 + v) * 2 + 0) * Hv + jrow] = hn[v];
      }
      produce(h0r + (size_t)((t + 1) & m0) * 8192, (unsigned)(t + 2), base_p, lq, hn);
    }
  } else if (bid < 64) {
    // ========== L1 slice wave: y0 consumed early, z-weights streamed ==========
    const int wg = bid - 32, j0 = wg << 4, jrow = j0 + lm;
    const int jj = jrow;
    const int base_p = (jj >> 5) * 512 + ((jj & 7) >> 2) * 256 + ((jj & 31) >> 3) * 64 + (jj & 3);
    v8bf wrh[16];
#pragma unroll
    for (int kb = 0; kb < 16; kb++) wrh[kb] = cvt8(Whr1 + (size_t)jrow * Hv + kb * 32 + lq * 8);
    float br = bhr1[jrow], bz = bhz1[jrow];
    {
      float h0v[4];
#pragma unroll
      for (int v = 0; v < 4; v++) h0v[v] = hs[((size_t)(lq * 4 + v) * 2 + 1) * Hv + jrow];
      produce(h1r, 1u, base_p, lq, h0v);
    }
    for (int t = 0; t < Sv; ++t) {
      // y0_t = h0 ring tag t+2 at slot (t+1)&m0 (L0 runs ahead: usually instant)
      v8bf ay[16];
      dead |= !consume(h0r + (size_t)((t + 1) & m0) * 8192, (unsigned)(t + 2), lane,
                       probe_off, ay, 0, lq, false, 0, dead);
      if (lane == 0) st32(prog + wg, (unsigned)(t + 1));
      v4f xr0 = {0, 0, 0, 0}, xr1 = {0, 0, 0, 0}, za = {0, 0, 0, 0}, zc = {0, 0, 0, 0};
#pragma unroll
      for (int kb = 0; kb < 16; kb += 2) {
        xr0 = MFMA(ay[kb], cvt8(Wxr1 + (size_t)jrow * Hv + kb * 32 + lq * 8), xr0);
        xr1 = MFMA(ay[kb + 1], cvt8(Wxr1 + (size_t)jrow * Hv + (kb + 1) * 32 + lq * 8), xr1);
        za = MFMA(ay[kb], cvt8(Wxz1 + (size_t)jrow * Hv + kb * 32 + lq * 8), za);
        zc = MFMA(ay[kb + 1], cvt8(Wxz1 + (size_t)jrow * Hv + (kb + 1) * 32 + lq * 8), zc);
      }
      v8bf ah[16]; float hvv[4];
      dead |= !consume(h1r + (size_t)(t & 7) * 8192, (unsigned)(t + 1), lane, probe_off,
                       ah, base_p, lq, true, hvv, dead);
      v4f r0 = {0, 0, 0, 0}, r1 = {0, 0, 0, 0};
#pragma unroll
      for (int kb = 0; kb < 16; kb += 2) {
        r0 = MFMA(ah[kb], wrh[kb], r0);
        r1 = MFMA(ah[kb + 1], wrh[kb + 1], r1);
      }
      float xr[4], u4[4];
#pragma unroll
      for (int v = 0; v < 4; v++) {
        xr[v] = xr0[v] + xr1[v];
        float r = sigf(xr[v] + r0[v] + r1[v] + br);
        u4[v] = r * hvv[v];
      }
      produce(u1r + (t & 1) * 8192, (unsigned)(t + 1), base_p, lq, u4);
      // ---- u-wait shadow: z h-part with streamed weights ----
#pragma unroll
      for (int kb = 0; kb < 16; kb += 2) {
        za = MFMA(ah[kb], cvt8(Whz1 + (size_t)jrow * Hv + kb * 32 + lq * 8), za);
        zc = MFMA(ah[kb + 1], cvt8(Whz1 + (size_t)jrow * Hv + (kb + 1) * 32 + lq * 8), zc);
      }
      if (t >= 7) {  // backpressure: out-waves must have consumed h1(t-7)
        unsigned need = (unsigned)(t - 6), rr = 0;
        for (;;) {
          unsigned pv = (lane < 8) ? ld32(oprog + lane) : 0xffffffffu;
          if (__all(pv >= need)) break;
          if (++rr > VALVE) { dead = true; break; }
          __builtin_amdgcn_s_sleep(1);
        }
      }
      v8bf au[16];
      dead |= !consume(u1r + (size_t)(t & 1) * 8192, (unsigned)(t + 1), lane, probe_off,
                       au, 0, lq, false, 0, dead);
      v4f g0 = {0, 0, 0, 0}, g1 = {0, 0, 0, 0};
#pragma unroll
      for (int kb = 0; kb < 16; kb += 2) {
        g0 = MFMA(au[kb], wrh[kb], g0);
        g1 = MFMA(au[kb + 1], wrh[kb + 1], g1);
      }
      float hn[4];
#pragma unroll
      for (int v = 0; v < 4; v++) {
        float zv = sigf(za[v] + zc[v] + bz);
        float g = tanh_fast(xr[v] + g0[v] + g1[v] + br);
        hn[v] = zv * hvv[v] + (1.f - zv) * g;
      }
      if (t == Sv - 1) {
#pragma unroll
        for (int v = 0; v < 4; v++)
          out[BSO + ((size_t)(lq * 4 + v) * 2 + 1) * Hv + jrow] = hn[v];
      }
      produce(h1r + (size_t)((t + 1) & 7) * 8192, (unsigned)(t + 2), base_p, lq, hn);
    }
  } else {
    // ========== out-head wave: out(t-1) = y1(t-1)@Why^T + by ==========
    const int o = bid - 64, orow = (o << 4) + lm;
    v8bf wo[16];
#pragma unroll
    for (int kb = 0; kb < 16; kb++)
      wo[kb] = cvt8(Why + (size_t)orow * Hv + kb * 32 + lq * 8);
    float bo = by[orow];
    for (int t = 0; t <= Sv; ++t) {
      v8bf ah[16];
      dead |= !consume(h1r + (size_t)(t & 7) * 8192, (unsigned)(t + 1), lane, probe_off,
                       ah, 0, lq, false, 0, dead);
      if (lane == 0) st32(oprog + o, (unsigned)(t + 1));
      if (t > 0) {
        v4f a0 = {0, 0, 0, 0}, a1 = {0, 0, 0, 0};
#pragma unroll
        for (int kb = 0; kb < 16; kb += 2) {
          a0 = MFMA(ah[kb], wo[kb], a0);
          a1 = MFMA(ah[kb + 1], wo[kb + 1], a1);
        }
#pragma unroll
        for (int v = 0; v < 4; v++)
          out[((size_t)(lq * 4 + v) * Sv + (t - 1)) * Ov + orow] = a0[v] + a1[v] + bo;
      }
    }
  }
}

extern "C" void kernel_launch(void* const* d_in, const int* in_sizes, int n_in,
                              void* d_out, int out_size, void* d_ws, size_t ws_size,
                              hipStream_t stream) {
  const float* x = (const float*)d_in[0];
  const float* hs = (const float*)d_in[1];
  const float* Wxz0 = (const float*)d_in[2];
  const float* Whz0 = (const float*)d_in[3];
  const float* bhz0 = (const float*)d_in[4];
  const float* Wxr0 = (const float*)d_in[5];
  const float* Whr0 = (const float*)d_in[6];
  const float* bhr0 = (const float*)d_in[7];
  const float* Wxz1 = (const float*)d_in[8];
  const float* Whz1 = (const float*)d_in[9];
  const float* bhz1 = (const float*)d_in[10];
  const float* Wxr1 = (const float*)d_in[11];
  const float* Whr1 = (const float*)d_in[12];
  const float* bhr1 = (const float*)d_in[13];
  const float* Why = (const float*)d_in[14];
  const float* by = (const float*)d_in[15];
  float* out = (float*)d_out;

  // y0-ring depth: largest pow2 (<=64, >=4) fitting ws. Slot = 32 KB tagged.
  int D = 64;
  while (D > 4 && 4096 + (size_t)(D + 12) * 32768 > ws_size) D >>= 1;

  hipMemsetAsync(d_ws, 0, 4096, stream);  // zero prog/oprog
  hipLaunchKernelGGL(gru_fused, dim3(72), dim3(64), 0, stream,
                     x, hs, Wxz0, Whz0, bhz0, Wxr0, Whr0, bhr0,
                     Wxz1, Whz1, bhz1, Wxr1, Whr1, bhr1, Why, by,
                     out, (char*)d_ws, D);
}

// Round 8
// 16083.891 us; speedup vs baseline: 2.2585x; 1.1903x over previous
//
#include <hip/hip_runtime.h>
#include <stdint.h>

// Problem constants
#define Bv 16
#define Sv 2048
#define Iv 128
#define Hv 512
#define Ov 128
#define VALVE (1u << 18)

typedef __bf16 v8bf __attribute__((ext_vector_type(8)));
typedef float v4f __attribute__((ext_vector_type(4)));
#define MFMA(a, b, c) __builtin_amdgcn_mfma_f32_16x16x32_bf16((a), (b), (c), 0, 0, 0)

__device__ __forceinline__ float sigf(float x) { return 1.0f / (1.0f + __expf(-x)); }
__device__ __forceinline__ float tanh_fast(float x) { return 2.0f / (1.0f + __expf(-2.0f * x)) - 1.0f; }
__device__ __forceinline__ unsigned f2bf(float f) {
  union { __bf16 h; unsigned short u; } c; c.h = (__bf16)f; return (unsigned)c.u;
}
__device__ __forceinline__ float bf2f(unsigned u) {
  union { __bf16 h; unsigned short u; } c; c.u = (unsigned short)u; return (float)c.h;
}
__device__ __forceinline__ v8bf cvt8(const float* p) {
  v8bf r;
#pragma unroll
  for (int i = 0; i < 8; i++) r[i] = (__bf16)p[i];
  return r;
}

// relaxed agent-scope atomics: sc1, bypass non-coherent per-XCD L2.
__device__ __forceinline__ uint64_t ld64(const uint64_t* p) {
  return __hip_atomic_load((uint64_t*)p, __ATOMIC_RELAXED, __HIP_MEMORY_SCOPE_AGENT);
}
__device__ __forceinline__ unsigned ld32(const unsigned* p) {
  return __hip_atomic_load((unsigned*)p, __ATOMIC_RELAXED, __HIP_MEMORY_SCOPE_AGENT);
}
__device__ __forceinline__ void st32(unsigned* p, unsigned v) {
  __hip_atomic_store(p, v, __ATOMIC_RELAXED, __HIP_MEMORY_SCOPE_AGENT);
}

// ==== Packed bf16 payload slot: 4096 dwords (16 KB) ====
// Element (b, j): kb=j>>5, lqd=(j&31)>>3, d=(j&7)>>1, pos=j&1
//   dword idx = kb*256 + (lqd*16 + b)*4 + d    (lo16 = pos0, hi16 = pos1)
// Consumer lane L=(lq*16+lm) reads its MFMA A-fragment for kb as dwords
//   kb*256 + L*4 + {0..3}  -> 64 lanes contiguous, 32 ld64 per 16 KB read.
// Sentinel: 32 dwords (one line) per slot, producer wg's word = slot tag.

__device__ __forceinline__ void read_pay(const unsigned* pay, int lane, v8bf* frag) {
  const uint64_t* p = (const uint64_t*)pay;
#pragma unroll
  for (int kb = 0; kb < 16; kb++) {
    uint64_t w0 = ld64(p + kb * 128 + lane * 2);
    uint64_t w1 = ld64(p + kb * 128 + lane * 2 + 1);
    union { v8bf v; uint64_t q[2]; } f;
    f.q[0] = w0; f.q[1] = w1;
    frag[kb] = f.v;
  }
}

// Producer: pack col-pairs via shfl, even lanes store 4 dwords. Fire-and-forget;
// caller must s_waitcnt(0) + sentinel-store to publish.
__device__ __forceinline__ void prod_pay(unsigned* pay, int lane, int lq,
                                         int kbp, int lqd, int dd, const float* vals) {
#pragma unroll
  for (int v = 0; v < 4; v++) {
    unsigned mb = f2bf(vals[v]);
    unsigned nb = (unsigned)__shfl_xor((int)mb, 1);
    if ((lane & 1) == 0)
      st32(pay + kbp * 256 + (lqd * 16 + lq * 4 + v) * 4 + dd, (mb & 0xffffu) | (nb << 16));
  }
}

__device__ __forceinline__ bool spin(const unsigned* s, unsigned tag, int lane, bool dead) {
  if (dead) return false;
  unsigned rr = 0;
  for (;;) {
    unsigned v = ld32(s + (lane & 31));
    if (__all(v == tag)) return true;
    if (++rr > VALVE) return false;  // valve: wrong answer beats hang
    __builtin_amdgcn_s_sleep(1);
  }
}

// Tagged-LDS handoff (tag in low 8 mantissa bits, rel err ~2^-16).
__device__ __forceinline__ void lds_post(unsigned* buf, int lm, int lq,
                                         const float* vals, unsigned tag8) {
#pragma unroll
  for (int v = 0; v < 4; v++) {
    union { float f; unsigned u; } c; c.f = vals[v];
    __hip_atomic_store(&buf[(lq * 4 + v) * 16 + lm], (c.u & ~255u) | tag8,
                       __ATOMIC_RELAXED, __HIP_MEMORY_SCOPE_WORKGROUP);
  }
}
__device__ __forceinline__ void lds_poll(unsigned* buf, int lm, int lq,
                                         float* vals, unsigned tag8) {
  for (unsigned rr = 0;;) {
    unsigned a[4];
#pragma unroll
    for (int v = 0; v < 4; v++)
      a[v] = __hip_atomic_load(&buf[(lq * 4 + v) * 16 + lm],
                               __ATOMIC_RELAXED, __HIP_MEMORY_SCOPE_WORKGROUP);
    unsigned acc = ((a[0] ^ tag8) | (a[1] ^ tag8) | (a[2] ^ tag8) | (a[3] ^ tag8)) & 255u;
    if (__all(acc == 0) || ++rr > VALVE) {
#pragma unroll
      for (int v = 0; v < 4; v++) {
        union { unsigned u; float f; } c; c.u = a[v] & ~255u; vals[v] = c.f;
      }
      break;
    }
  }
}

// x f32 fragment load (A-layout, b=lm) + convert
__device__ __forceinline__ void ldx(const float* x, int t, int lm, int lq, float4* xf) {
#pragma unroll
  for (int kb = 0; kb < 4; kb++) {
    const float* pp = x + ((size_t)lm * Sv + t) * Iv + kb * 32 + lq * 8;
    xf[kb * 2] = *(const float4*)pp;
    xf[kb * 2 + 1] = *(const float4*)(pp + 4);
  }
}
__device__ __forceinline__ void cvx(const float4* xf, v8bf* ax) {
#pragma unroll
  for (int kb = 0; kb < 4; kb++) {
    v8bf a;
    const float* f0 = (const float*)&xf[kb * 2];
    const float* f1 = (const float*)&xf[kb * 2 + 1];
#pragma unroll
    for (int i = 0; i < 4; i++) { a[i] = (__bf16)f0[i]; a[i + 4] = (__bf16)f1[i]; }
    ax[kb] = a;
  }
}

__global__ __launch_bounds__(128, 1) void gru_fused(
    const float* __restrict__ x, const float* __restrict__ hs,
    const float* __restrict__ Wxz0, const float* __restrict__ Whz0, const float* __restrict__ bhz0,
    const float* __restrict__ Wxr0, const float* __restrict__ Whr0, const float* __restrict__ bhr0,
    const float* __restrict__ Wxz1, const float* __restrict__ Whz1, const float* __restrict__ bhz1,
    const float* __restrict__ Wxr1, const float* __restrict__ Whr1, const float* __restrict__ bhr1,
    const float* __restrict__ Why, const float* __restrict__ by,
    float* __restrict__ out, char* __restrict__ ws, int D) {
  const int tid = threadIdx.x;
  const int wv = tid >> 6;
  const int lane = tid & 63;
  const int lm = lane & 15;
  const int lq = lane >> 4;
  const int m0 = D - 1;
  const size_t BSO = (size_t)Bv * Sv * Ov;

  unsigned* prog = (unsigned*)ws;           // [32] L1 z-wave y0 progress
  unsigned* oprog = (unsigned*)(ws + 256);  // [8] out-wave h1 progress
  unsigned* sent = (unsigned*)(ws + 1024);
  unsigned* h0s = sent;                     // [D][32]
  unsigned* h1s = h0s + D * 32;             // [8][32]
  unsigned* u0s = h1s + 8 * 32;             // [2][32]
  unsigned* u1s = u0s + 2 * 32;             // [2][32]
  unsigned* pay = (unsigned*)(ws + 65536);
  unsigned* h0d = pay;                      // [D][4096]
  unsigned* h1d = h0d + (size_t)D * 4096;   // [8][4096]
  unsigned* u0d = h1d + 8 * 4096;           // [2][4096]
  unsigned* u1d = u0d + 2 * 4096;           // [2][4096]

  __shared__ unsigned zbuf[4 * 256];  // z handoff ring
  __shared__ unsigned xbuf[4 * 256];  // L1 xr handoff ring

  bool dead = false;
  const int bid = blockIdx.x;

  if (bid >= 64) {
    // ============ out-head wave: out(t-1) = y1(t-1)@Why^T + by ============
    if (wv != 0) return;
    const int o = bid - 64, orow = (o << 4) + lm;
    v8bf wo[16];
#pragma unroll
    for (int kb = 0; kb < 16; kb++)
      wo[kb] = cvt8(Why + (size_t)orow * Hv + kb * 32 + lq * 8);
    float bo = by[orow];
    for (int t = 0; t <= Sv; ++t) {
      v8bf ah[16];
      dead |= !spin(h1s + (t & 7) * 32, (unsigned)(t + 1), lane, dead);
      read_pay(h1d + (size_t)(t & 7) * 4096, lane, ah);
      if (t > 0) {
        v4f a0 = {0, 0, 0, 0}, a1 = {0, 0, 0, 0};
#pragma unroll
        for (int kb = 0; kb < 16; kb += 2) {
          a0 = MFMA(ah[kb], wo[kb], a0);
          a1 = MFMA(ah[kb + 1], wo[kb + 1], a1);
        }
#pragma unroll
        for (int v = 0; v < 4; v++)
          out[((size_t)(lq * 4 + v) * Sv + (t - 1)) * Ov + orow] = a0[v] + a1[v] + bo;
      } else {
        __builtin_amdgcn_s_waitcnt(0);  // payload reads done before progress post
      }
      if (lane == 0) st32(oprog + o, (unsigned)(t + 1));
    }
    return;
  }

  const bool L1 = (bid >= 32);
  const int wg = bid & 31;
  const int j0 = wg << 4;
  const int jrow = j0 + lm;
  // producer packing indices for own column jrow
  const int kbp = jrow >> 5, lqd = (jrow & 31) >> 3, dd = (jrow & 7) >> 1;
  // hv dword index for (b=lq*4+v, j=jrow) equals the produce index:
  const int hvbase = kbp * 256 + (lqd * 16 + lq * 4) * 4 + dd;

  // zero LDS rings, then one startup barrier (the only barrier in the kernel)
  for (int i = tid; i < 1024; i += 128) { zbuf[i] = 0; xbuf[i] = 0; }
  __syncthreads();

  if (!L1) {
    if (wv == 0) {
      // ===== L0 driver: r -> u -> g -> h' ; z from helper =====
      v8bf wrx[4], wrh[16];
#pragma unroll
      for (int kb = 0; kb < 4; kb++) wrx[kb] = cvt8(Wxr0 + (size_t)jrow * Iv + kb * 32 + lq * 8);
#pragma unroll
      for (int kb = 0; kb < 16; kb++) wrh[kb] = cvt8(Whr0 + (size_t)jrow * Hv + kb * 32 + lq * 8);
      float br = bhr0[jrow];
      {  // initial state
        float h0v[4];
#pragma unroll
        for (int v = 0; v < 4; v++) h0v[v] = hs[((size_t)(lq * 4 + v) * 2 + 0) * Hv + jrow];
        prod_pay(h0d, lane, lq, kbp, lqd, dd, h0v);
        __builtin_amdgcn_s_waitcnt(0);
        if (lane == 0) st32(h0s + wg, 1u);
      }
      float4 xf[8];
      ldx(x, 0, lm, lq, xf);
      for (int t = 0; t < Sv; ++t) {
        dead |= !spin(h0s + (t & m0) * 32, (unsigned)(t + 1), lane, dead);
        const unsigned* hp = h0d + (size_t)(t & m0) * 4096;
        v8bf ah[16];
        read_pay(hp, lane, ah);
        float hvv[4];
#pragma unroll
        for (int v = 0; v < 4; v++) {
          unsigned hw = ld32(hp + hvbase + v * 4);
          hvv[v] = bf2f((lane & 1) ? (hw >> 16) : (hw & 0xffffu));
        }
        v8bf ax[4];
        cvx(xf, ax);
        v4f axr = {0, 0, 0, 0}, r0 = {0, 0, 0, 0}, r1 = {0, 0, 0, 0};
#pragma unroll
        for (int kb = 0; kb < 4; kb++) axr = MFMA(ax[kb], wrx[kb], axr);
#pragma unroll
        for (int kb = 0; kb < 16; kb += 2) {
          r0 = MFMA(ah[kb], wrh[kb], r0);
          r1 = MFMA(ah[kb + 1], wrh[kb + 1], r1);
        }
        float u4[4];
#pragma unroll
        for (int v = 0; v < 4; v++) {
          float r = sigf(axr[v] + r0[v] + r1[v] + br);
          u4[v] = r * hvv[v];
        }
        prod_pay(u0d + (t & 1) * 4096, lane, lq, kbp, lqd, dd, u4);
        __builtin_amdgcn_s_waitcnt(0);
        if (lane == 0) st32(u0s + (t & 1) * 32 + wg, (unsigned)(t + 1));
        if (t + 1 < Sv) ldx(x, t + 1, lm, lq, xf);  // prefetch in u-wait shadow
        if (t >= D) {  // backpressure: L1 z-waves must have consumed y0(t-D)
          unsigned need = (unsigned)(t - D + 1), rr = 0;
          for (;;) {
            unsigned pv = (lane < 32) ? ld32(prog + lane) : 0xffffffffu;
            if (__all(pv >= need)) break;
            if (++rr > VALVE) { dead = true; break; }
            __builtin_amdgcn_s_sleep(1);
          }
        }
        dead |= !spin(u0s + (t & 1) * 32, (unsigned)(t + 1), lane, dead);
        v8bf au[16];
        read_pay(u0d + (size_t)(t & 1) * 4096, lane, au);
        v4f g0 = {0, 0, 0, 0}, g1 = {0, 0, 0, 0};
#pragma unroll
        for (int kb = 0; kb < 16; kb += 2) {
          g0 = MFMA(au[kb], wrh[kb], g0);
          g1 = MFMA(au[kb + 1], wrh[kb + 1], g1);
        }
        float zv[4];
        lds_poll(zbuf + (t & 3) * 256, lm, lq, zv, (unsigned)(t + 1) & 255u);
        float hn[4];
#pragma unroll
        for (int v = 0; v < 4; v++) {
          float g = tanh_fast(axr[v] + g0[v] + g1[v] + br);  // faithful source bug
          hn[v] = zv[v] * hvv[v] + (1.f - zv[v]) * g;
        }
        if (t == Sv - 1) {
#pragma unroll
          for (int v = 0; v < 4; v++)
            out[BSO + ((size_t)(lq * 4 + v) * 2 + 0) * Hv + jrow] = hn[v];
        }
        prod_pay(h0d + (size_t)((t + 1) & m0) * 4096, lane, lq, kbp, lqd, dd, hn);
        __builtin_amdgcn_s_waitcnt(0);
        if (lane == 0) st32(h0s + ((t + 1) & m0) * 32 + wg, (unsigned)(t + 2));
      }
    } else {
      // ===== L0 z-wave: z = sig(x@Wxz0 + h@Whz0 + bz) =====
      v8bf wzx[4], wzh[16];
#pragma unroll
      for (int kb = 0; kb < 4; kb++) wzx[kb] = cvt8(Wxz0 + (size_t)jrow * Iv + kb * 32 + lq * 8);
#pragma unroll
      for (int kb = 0; kb < 16; kb++) wzh[kb] = cvt8(Whz0 + (size_t)jrow * Hv + kb * 32 + lq * 8);
      float bz = bhz0[jrow];
      float4 xf[8];
      ldx(x, 0, lm, lq, xf);
      for (int t = 0; t < Sv; ++t) {
        v8bf ax[4];
        cvx(xf, ax);
        v4f z0 = {0, 0, 0, 0}, z1 = {0, 0, 0, 0};
#pragma unroll
        for (int kb = 0; kb < 4; kb++) z0 = MFMA(ax[kb], wzx[kb], z0);
        dead |= !spin(h0s + (t & m0) * 32, (unsigned)(t + 1), lane, dead);
        v8bf ah[16];
        read_pay(h0d + (size_t)(t & m0) * 4096, lane, ah);
#pragma unroll
        for (int kb = 0; kb < 16; kb += 2) {
          z0 = MFMA(ah[kb], wzh[kb], z0);
          z1 = MFMA(ah[kb + 1], wzh[kb + 1], z1);
        }
        float zv[4];
#pragma unroll
        for (int v = 0; v < 4; v++) zv[v] = sigf(z0[v] + z1[v] + bz);
        lds_post(zbuf + (t & 3) * 256, lm, lq, zv, (unsigned)(t + 1) & 255u);
        if (t + 1 < Sv) ldx(x, t + 1, lm, lq, xf);
      }
    }
  } else {
    if (wv == 0) {
      // ===== L1 driver: r -> u -> g -> h' ; xr & z from helper =====
      v8bf wrh[16];
#pragma unroll
      for (int kb = 0; kb < 16; kb++) wrh[kb] = cvt8(Whr1 + (size_t)jrow * Hv + kb * 32 + lq * 8);
      float br = bhr1[jrow];
      {
        float h0v[4];
#pragma unroll
        for (int v = 0; v < 4; v++) h0v[v] = hs[((size_t)(lq * 4 + v) * 2 + 1) * Hv + jrow];
        prod_pay(h1d, lane, lq, kbp, lqd, dd, h0v);
        __builtin_amdgcn_s_waitcnt(0);
        if (lane == 0) st32(h1s + wg, 1u);
      }
      for (int t = 0; t < Sv; ++t) {
        dead |= !spin(h1s + (t & 7) * 32, (unsigned)(t + 1), lane, dead);
        const unsigned* hp = h1d + (size_t)(t & 7) * 4096;
        v8bf ah[16];
        read_pay(hp, lane, ah);
        float hvv[4];
#pragma unroll
        for (int v = 0; v < 4; v++) {
          unsigned hw = ld32(hp + hvbase + v * 4);
          hvv[v] = bf2f((lane & 1) ? (hw >> 16) : (hw & 0xffffu));
        }
        float xr[4];
        lds_poll(xbuf + (t & 3) * 256, lm, lq, xr, (unsigned)(t + 1) & 255u);
        v4f r0 = {0, 0, 0, 0}, r1 = {0, 0, 0, 0};
#pragma unroll
        for (int kb = 0; kb < 16; kb += 2) {
          r0 = MFMA(ah[kb], wrh[kb], r0);
          r1 = MFMA(ah[kb + 1], wrh[kb + 1], r1);
        }
        float u4[4];
#pragma unroll
        for (int v = 0; v < 4; v++) {
          float r = sigf(xr[v] + r0[v] + r1[v] + br);
          u4[v] = r * hvv[v];
        }
        prod_pay(u1d + (t & 1) * 4096, lane, lq, kbp, lqd, dd, u4);
        __builtin_amdgcn_s_waitcnt(0);
        if (lane == 0) st32(u1s + (t & 1) * 32 + wg, (unsigned)(t + 1));
        if (t >= 7) {  // backpressure: out-waves must have consumed h1(t-7)
          unsigned need = (unsigned)(t - 6), rr = 0;
          for (;;) {
            unsigned pv = (lane < 8) ? ld32(oprog + lane) : 0xffffffffu;
            if (__all(pv >= need)) break;
            if (++rr > VALVE) { dead = true; break; }
            __builtin_amdgcn_s_sleep(1);
          }
        }
        dead |= !spin(u1s + (t & 1) * 32, (unsigned)(t + 1), lane, dead);
        v8bf au[16];
        read_pay(u1d + (size_t)(t & 1) * 4096, lane, au);
        v4f g0 = {0, 0, 0, 0}, g1 = {0, 0, 0, 0};
#pragma unroll
        for (int kb = 0; kb < 16; kb += 2) {
          g0 = MFMA(au[kb], wrh[kb], g0);
          g1 = MFMA(au[kb + 1], wrh[kb + 1], g1);
        }
        float zv[4];
        lds_poll(zbuf + (t & 3) * 256, lm, lq, zv, (unsigned)(t + 1) & 255u);
        float hn[4];
#pragma unroll
        for (int v = 0; v < 4; v++) {
          float g = tanh_fast(xr[v] + g0[v] + g1[v] + br);
          hn[v] = zv[v] * hvv[v] + (1.f - zv[v]) * g;
        }
        if (t == Sv - 1) {
#pragma unroll
          for (int v = 0; v < 4; v++)
            out[BSO + ((size_t)(lq * 4 + v) * 2 + 1) * Hv + jrow] = hn[v];
        }
        prod_pay(h1d + (size_t)((t + 1) & 7) * 4096, lane, lq, kbp, lqd, dd, hn);
        __builtin_amdgcn_s_waitcnt(0);
        if (lane == 0) st32(h1s + ((t + 1) & 7) * 32 + wg, (unsigned)(t + 2));
      }
    } else {
      // ===== L1 z-wave: xr = y0@Wxr1 (posted early); z = sig(y0@Wxz1 + h1@Whz1 + bz) =====
      v8bf wxr[16], wxz[16], wzh[16];
#pragma unroll
      for (int kb = 0; kb < 16; kb++) {
        wxr[kb] = cvt8(Wxr1 + (size_t)jrow * Hv + kb * 32 + lq * 8);
        wxz[kb] = cvt8(Wxz1 + (size_t)jrow * Hv + kb * 32 + lq * 8);
        wzh[kb] = cvt8(Whz1 + (size_t)jrow * Hv + kb * 32 + lq * 8);
      }
      float bz = bhz1[jrow];
      for (int t = 0; t < Sv; ++t) {
        // y0(t) = h0 ring tag t+2 at slot (t+1)&m0
        dead |= !spin(h0s + ((t + 1) & m0) * 32, (unsigned)(t + 2), lane, dead);
        v8bf ay[16];
        read_pay(h0d + (size_t)((t + 1) & m0) * 4096, lane, ay);
        v4f x0 = {0, 0, 0, 0}, x1 = {0, 0, 0, 0}, z0 = {0, 0, 0, 0}, z1 = {0, 0, 0, 0};
#pragma unroll
        for (int kb = 0; kb < 16; kb += 2) {
          x0 = MFMA(ay[kb], wxr[kb], x0);
          x1 = MFMA(ay[kb + 1], wxr[kb + 1], x1);
        }
        float xv[4];
#pragma unroll
        for (int v = 0; v < 4; v++) xv[v] = x0[v] + x1[v];
        lds_post(xbuf + (t & 3) * 256, lm, lq, xv, (unsigned)(t + 1) & 255u);
#pragma unroll
        for (int kb = 0; kb < 16; kb += 2) {
          z0 = MFMA(ay[kb], wxz[kb], z0);
          z1 = MFMA(ay[kb + 1], wxz[kb + 1], z1);
        }
        __builtin_amdgcn_s_waitcnt(0);  // y0 reads complete before progress post
        if (lane == 0) st32(prog + wg, (unsigned)(t + 1));
        dead |= !spin(h1s + (t & 7) * 32, (unsigned)(t + 1), lane, dead);
        v8bf ah[16];
        read_pay(h1d + (size_t)(t & 7) * 4096, lane, ah);
#pragma unroll
        for (int kb = 0; kb < 16; kb += 2) {
          z0 = MFMA(ah[kb], wzh[kb], z0);
          z1 = MFMA(ah[kb + 1], wzh[kb + 1], z1);
        }
        float zv[4];
#pragma unroll
        for (int v = 0; v < 4; v++) zv[v] = sigf(z0[v] + z1[v] + bz);
        lds_post(zbuf + (t & 3) * 256, lm, lq, zv, (unsigned)(t + 1) & 255u);
      }
    }
  }
}

extern "C" void kernel_launch(void* const* d_in, const int* in_sizes, int n_in,
                              void* d_out, int out_size, void* d_ws, size_t ws_size,
                              hipStream_t stream) {
  const float* x = (const float*)d_in[0];
  const float* hs = (const float*)d_in[1];
  const float* Wxz0 = (const float*)d_in[2];
  const float* Whz0 = (const float*)d_in[3];
  const float* bhz0 = (const float*)d_in[4];
  const float* Wxr0 = (const float*)d_in[5];
  const float* Whr0 = (const float*)d_in[6];
  const float* bhr0 = (const float*)d_in[7];
  const float* Wxz1 = (const float*)d_in[8];
  const float* Whz1 = (const float*)d_in[9];
  const float* bhz1 = (const float*)d_in[10];
  const float* Wxr1 = (const float*)d_in[11];
  const float* Whr1 = (const float*)d_in[12];
  const float* bhr1 = (const float*)d_in[13];
  const float* Why = (const float*)d_in[14];
  const float* by = (const float*)d_in[15];
  float* out = (float*)d_out;

  // y0-ring depth: largest pow2 (<=64, >=4) fitting ws. Payload slot = 16 KB.
  int D = 64;
  while (D > 4 && 65536 + (size_t)(D + 12) * 16384 > ws_size) D >>= 1;

  hipMemsetAsync(d_ws, 0, 65536, stream);  // zero prog/oprog/sentinels
  hipLaunchKernelGGL(gru_fused, dim3(72), dim3(128), 0, stream,
                     x, hs, Wxz0, Whz0, bhz0, Wxr0, Whr0, bhr0,
                     Wxz1, Whz1, bhz1, Wxr1, Whr1, bhr1, Why, by,
                     out, (char*)d_ws, D);
}